// Round 1
// 103.862 us; speedup vs baseline: 1.0847x; 1.0847x over previous
//
#include <hip/hip_runtime.h>

#define B_ROWS   8192
#define BMASK    8191
#define DIM      128
#define CTILE    64          // columns per tile
#define CHUNK0   20          // z0 col-tiles per block
#define CHUNK1   32          // z1 col-tiles per block
#define NZ1      256         // z1 blocks = 64 panels * (128/CHUNK1)
#define BLK64    16384       // bytes per packed 64-row block (64*128*2)
#define NBUF     3           // LDS staging ring depth

typedef __attribute__((ext_vector_type(8)))  __bf16 bf16x8;
typedef __attribute__((ext_vector_type(2)))  __bf16 bf16x2;
typedef __attribute__((ext_vector_type(16))) float  f32x16;

// sqrt(log2(e)/0.07) folded symmetrically into both row normalizations.
#define RBSCALE 4.5398159f

__device__ __forceinline__ float fast_exp2(float x) {
#if __has_builtin(__builtin_amdgcn_exp2f)
    return __builtin_amdgcn_exp2f(x);
#else
    return exp2f(x);
#endif
}

// One wave per row: norm -> scale -> bf16 -> k-major packed layout
// packed[row>>6][granule=k/8][row&63][8 bf16]. Block 0 zeroes accumulators.
__global__ __launch_bounds__(256)
void prep_kernel(const float* __restrict__ e1, const float* __restrict__ e2,
                 char* __restrict__ p1, char* __restrict__ p2,
                 float* __restrict__ acc) {
    if (blockIdx.x == 0 && threadIdx.x < 4) acc[threadIdx.x] = 0.f;
    int gw   = (blockIdx.x * 256 + threadIdx.x) >> 6;   // 0..16383
    int lane = threadIdx.x & 63;
    const float* src; char* dst; int row;
    if (gw < B_ROWS) { src = e1; dst = p1; row = gw; }
    else             { src = e2; dst = p2; row = gw - B_ROWS; }
    float2 v = ((const float2*)(src + (size_t)row * DIM))[lane];
    float ss = v.x * v.x + v.y * v.y;
#pragma unroll
    for (int o = 32; o > 0; o >>= 1) ss += __shfl_xor(ss, o);   // butterfly: all lanes get total
    float rb = RBSCALE / sqrtf(ss);
    bf16x2 pk = { (__bf16)(v.x * rb), (__bf16)(v.y * rb) };
    size_t off = (size_t)(row >> 6) * BLK64 + (size_t)(lane >> 2) * 1024
               + (size_t)(row & 63) * 16 + (size_t)(lane & 3) * 4;
    *(bf16x2*)(dst + off) = pk;
}

// Epilogue for one 64x32 accumulator pair: exp2 + (optional) mask + sum.
// 4-way partial sums break the serial dependent-add chain.
template <bool MASKED>
__device__ __forceinline__ float tile_sum(const f32x16& a0, const f32x16& a1,
                                          int i00, int c) {
    float s0 = 0.f, s1 = 0.f, s2 = 0.f, s3 = 0.f;
#pragma unroll
    for (int g = 0; g < 2; ++g) {
        const f32x16& a = g ? a1 : a0;
        int ib = i00 + g * 32;
#pragma unroll
        for (int r = 0; r < 16; ++r) {
            float ev = fast_exp2(a[r]);
            float add;
            if (MASKED) {
                int i = ib + (r & 3) + 8 * (r >> 2);   // m74/m101 C/D row map
                int d = (c - i) & BMASK;               // (c-i) mod B
                add = (d > i) ? ev : 0.f;
            } else {
                add = ev;
            }
            if      ((r & 3) == 0) s0 += add;
            else if ((r & 3) == 1) s1 += add;
            else if ((r & 3) == 2) s2 += add;
            else                   s3 += add;
        }
    }
    return (s0 + s1) + (s2 + s3);
}

// Persistent-panel blocks: 128-row A panel in registers, loop over 64-col B tiles.
// New schedule: 3-buffer LDS ring with counted vmcnt + raw barriers (2 stages in
// flight across barriers), and a deferred (even/odd) exp epilogue so the VALU
// work of tile k-1 overlaps the MFMAs of tile k.
// 500 blocks @ 2 blocks/CU (reg-limited) -> single dispatch round.
__global__ __launch_bounds__(256, 2)
void pair_kernel(const char* __restrict__ P1, const char* __restrict__ P2,
                 float* __restrict__ accg, float* __restrict__ out,
                 int nblocks) {
    __shared__ __align__(16) __bf16 Bbuf[NBUF][8192];   // 3 x 16 KB ring
    __shared__ float red[4];

    const int tid = threadIdx.x;
    const int b   = blockIdx.x;

    // ---- block -> (z, panel p, tile chunk [k0,k1)) ----  (z1 blocks first: balance)
    int z, p, k0, k1;
    if (b < NZ1) {
        z = 1; p = b >> 2; k0 = (b & 3) * CHUNK1; k1 = k0 + CHUNK1;
    } else {
        z = 0;
        int bb0 = b - NZ1, accb = 0;
        p = 0;
        for (;; ++p) {
            int i0t = 128 * p;
            int e1t = (i0t > 128) ? i0t : 128;
            int cnt = 2 + (B_ROWS - e1t) / 64;
            int nb  = (cnt + CHUNK0 - 1) / CHUNK0;
            if (bb0 < accb + nb) {
                int s = bb0 - accb;
                k0 = s * CHUNK0;
                k1 = (k0 + CHUNK0 < cnt) ? (k0 + CHUNK0) : cnt;
                break;
            }
            accb += nb;
        }
    }
    const int i0 = 128 * p;
    const int e1 = (i0 > 128) ? i0 : 128;

    const char* Bpack = (z == 0) ? P1 : P2;

    // tile index k -> column origin c0; masked flag (z=0 only)
    auto tile_c0 = [&](int k) -> int {
        if (z) return k * CTILE;
        int e = (k == 0) ? 64 : e1 + (k - 1) * 64;
        return (i0 + e) & BMASK;
    };
    auto tile_masked = [&](int k) -> bool {
        if (z) return false;
        int e = (k == 0) ? 64 : e1 + (k - 1) * 64;
        return (e < i0 + 256) || (e > 8128);
    };

    const int w  = tid >> 6, lane = tid & 63;
    const int w2 = w >> 1, wc = w & 1;
    const int l  = lane & 31, h = lane >> 5;

    // ---- A panel -> registers: rows i0 + w2*64 + [0,64), k-major packed ----
    bf16x8 af[2][8];
    {
        const char* ap = P1 + (size_t)(p * 2 + w2) * BLK64;
#pragma unroll
        for (int g = 0; g < 2; ++g)
#pragma unroll
            for (int s = 0; s < 8; ++s)
                af[g][s] = *(const bf16x8*)(ap + (size_t)(s * 2 + h) * 1024
                                               + (size_t)(g * 32 + l) * 16);
    }

    // ---- async stage into ring buffer: 16 KB tile, lane-linear, 4 vmcnt items/wave ----
    auto stage = [&](int k) {
        int u  = k - k0;
        int bi = u % NBUF;
        const char* gp = Bpack + (size_t)(tile_c0(k) >> 6) * BLK64 + (size_t)tid * 16;
        char*       lp = (char*)&Bbuf[bi][0] + (size_t)tid * 16;
#pragma unroll
        for (int r = 0; r < 4; ++r)
            __builtin_amdgcn_global_load_lds(
                (const __attribute__((address_space(1))) unsigned int*)(gp + r * 4096),
                (__attribute__((address_space(3))) unsigned int*)(lp + r * 4096),
                16, 0, 0);
    };

    const int i00 = i0 + w2 * 64 + 4 * h;   // epilogue row base for this lane
    const int cb  = wc * 32 + l;            // col offset within tile

    float sacc = 0.f;

    // prologue: fill the pipeline (2 stages in flight)
    stage(k0);
    if (k0 + 1 < k1) stage(k0 + 1);

    // One tile's barrier-to-MFMA phase. vmcnt(4) keeps the next stage's 4 loads
    // in flight across the barrier; buffer (k+2)%3 == (k-1)%3 is free because all
    // waves passed this barrier after consuming tile k-1.
    auto compute_tile = [&](f32x16& r0, f32x16& r1, int k, int& cS, bool& mS) {
        if (k + 1 < k1) { asm volatile("s_waitcnt vmcnt(4)" ::: "memory"); }
        else            { asm volatile("s_waitcnt vmcnt(0)" ::: "memory"); }
        __builtin_amdgcn_s_barrier();
        __builtin_amdgcn_sched_barrier(0);
        if (k + 2 < k1) stage(k + 2);
        __builtin_amdgcn_sched_barrier(0);

#pragma unroll
        for (int r = 0; r < 16; ++r) { r0[r] = 0.f; r1[r] = 0.f; }

        const char* bbp = (const char*)&Bbuf[(k - k0) % NBUF][0]
                        + (size_t)cb * 16 + (size_t)h * 1024;
#pragma unroll
        for (int s = 0; s < 8; ++s) {
            bf16x8 bf = *(const bf16x8*)(bbp + (size_t)s * 2048);
            r0 = __builtin_amdgcn_mfma_f32_32x32x16_bf16(af[0][s], bf, r0, 0, 0, 0);
            r1 = __builtin_amdgcn_mfma_f32_32x32x16_bf16(af[1][s], bf, r1, 0, 0, 0);
        }
        cS = tile_c0(k) + cb;
        mS = tile_masked(k);
    };

    auto epi = [&](const f32x16& a0, const f32x16& a1, int c, bool m) {
        sacc += m ? tile_sum<true >(a0, a1, i00, c)
                  : tile_sum<false>(a0, a1, i00, c);
    };

    // Software-pipelined main loop: epilogue of tile k-1 overlaps MFMAs of tile k.
    // Static even/odd accumulator sets (rule: no runtime-indexed vector arrays).
    f32x16 aE0, aE1, aO0, aO1;
    int cE, cO; bool mE, mO;

    int k = k0;
    compute_tile(aE0, aE1, k, cE, mE); ++k;
    while (k + 1 < k1) {
        compute_tile(aO0, aO1, k, cO, mO); epi(aE0, aE1, cE, mE); ++k;
        compute_tile(aE0, aE1, k, cE, mE); epi(aO0, aO1, cO, mO); ++k;
    }
    if (k < k1) {
        compute_tile(aO0, aO1, k, cO, mO); epi(aE0, aE1, cE, mE);
        epi(aO0, aO1, cO, mO);
    } else {
        epi(aE0, aE1, cE, mE);
    }

#pragma unroll
    for (int o = 32; o > 0; o >>= 1) sacc += __shfl_down(sacc, o);
    if (lane == 0) red[w] = sacc;
    __syncthreads();
    if (tid == 0) {
        atomicAdd(&accg[z], red[0] + red[1] + red[2] + red[3]);
        __threadfence();
        unsigned prev = atomicAdd((unsigned*)&accg[2], 1u);
        if (prev == (unsigned)(nblocks - 1)) {
            float l1 = atomicAdd(&accg[0], 0.f);
            float l2 = atomicAdd(&accg[1], 0.f);
            out[0] = -logf(l1 / l2);
        }
    }
}

extern "C" void kernel_launch(void* const* d_in, const int* in_sizes, int n_in,
                              void* d_out, int out_size, void* d_ws, size_t ws_size,
                              hipStream_t stream) {
    (void)in_sizes; (void)n_in; (void)out_size; (void)ws_size;
    const float* e1 = (const float*)d_in[0];
    const float* e2 = (const float*)d_in[1];
    float* out = (float*)d_out;
    char*  ws  = (char*)d_ws;

    float* acc = (float*)ws;                       // 16 B: l1, l2, counter, pad
    char*  p1  = ws + 4096;                        // 2 MB packed E1
    char*  p2  = ws + 4096 + 2097152;              // 2 MB packed E2

    // z0 block count (must match device-side mapping; z1 blocks come first)
    int nz0 = 0;
    for (int p = 0; p < 64; ++p) {
        int i0 = 128 * p;
        int e1t = (i0 > 128) ? i0 : 128;
        int cnt = 2 + (B_ROWS - e1t) / 64;
        nz0 += (cnt + CHUNK0 - 1) / CHUNK0;
    }
    int nblocks = NZ1 + nz0;   // 256 + 244 = 500 <= 512 (2 blocks/CU) -> one round

    prep_kernel<<<dim3(4096), dim3(256), 0, stream>>>(e1, e2, p1, p2, acc);
    pair_kernel<<<dim3(nblocks), dim3(256), 0, stream>>>(p1, p2, acc, out, nblocks);
}